// Round 11
// baseline (235.899 us; speedup 1.0000x reference)
//
#include <hip/hip_runtime.h>

#define D_MODEL 1024
#define N_MOD   4
#define EB      32     // e-chunks in stage 1
#define ECHUNK  32     // e per chunk
#define EPW     8      // e per esub-wave

typedef float fx4 __attribute__((ext_vector_type(4)));

// ============ Stage 1 (R8 verbatim): partial[m][eb][d] ============
__global__ __launch_bounds__(256) void weff_partial_kernel(
    const fx4* __restrict__ Wg4,   // [1024][256] fx4
    const float* __restrict__ Wr,  // [4][1024]
    fx4* __restrict__ partial4)    // [4][EB][256] fx4
{
    const int t    = threadIdx.x;
    const int esub = t >> 6;
    const int d4   = t & 63;
    const int eb   = blockIdx.x;
    const int dc   = blockIdx.y;
    const int d4g  = dc * 64 + d4;
    const int e0   = eb * ECHUNK + esub * EPW;

    fx4 acc[N_MOD];
    #pragma unroll
    for (int m = 0; m < N_MOD; ++m) acc[m] = (fx4)(0.f);
    #pragma unroll
    for (int k = 0; k < EPW; ++k) {
        const int e = e0 + k;
        const fx4 wg = Wg4[e * 256 + d4g];
        #pragma unroll
        for (int m = 0; m < N_MOD; ++m)
            acc[m] += Wr[m * D_MODEL + e] * wg;   // wave-uniform scalar Wr load
    }
    __shared__ fx4 red[4][N_MOD][64];
    #pragma unroll
    for (int m = 0; m < N_MOD; ++m) red[esub][m][d4] = acc[m];
    __syncthreads();
    const int m2 = t >> 6;
    partial4[(m2 * EB + eb) * 256 + d4g] =
        red[0][m2][d4] + red[1][m2][d4] + red[2][m2][d4] + red[3][m2][d4];
}

// ============ Stage 2 (R8 verbatim): Weff[m][d] = sum_eb partial ============
__global__ __launch_bounds__(256) void weff_reduce_kernel(
    const float* __restrict__ partial, float* __restrict__ Weff)
{
    const int idx = blockIdx.x * 256 + threadIdx.x;
    const int m = idx >> 10;
    const int d = idx & (D_MODEL - 1);
    float s = 0.f;
    #pragma unroll
    for (int eb = 0; eb < EB; ++eb)
        s += partial[(m * EB + eb) * D_MODEL + d];
    Weff[idx] = s;
}

// ============ Main v4: LDS-Weff, 64-VGPR cap, 32 waves/CU, 4 rows/wave ============
__global__ __launch_bounds__(256, 8) void router_main_kernel(
    const float* __restrict__ h,     // [B, 1024]
    const float* __restrict__ Weff,  // [4, 1024]
    float* __restrict__ out,         // [4][B][4]
    int B)
{
    __shared__ fx4 wlds[N_MOD][4][64];    // [m][c][lane], 16 KB
    const int t = threadIdx.x;

    // Stage Weff into LDS: 1024 fx4, 256 threads x 4.
    const fx4* __restrict__ W4 = (const fx4*)Weff;
    #pragma unroll
    for (int j = 0; j < 4; ++j) {
        const int idx = j * 256 + t;       // = m*256 + c*64 + l
        ((fx4*)wlds)[idx] = W4[idx];
    }
    __syncthreads();

    const int lane = t & 63;
    const int wave = t >> 6;
    float4* __restrict__ out4 = (float4*)out;   // [4][B] float4s
    const int wid  = blockIdx.x * 4 + wave;
    const int step = gridDim.x * 4 * 4;

    for (int row0 = wid * 4; row0 < B; row0 += step) {
        const fx4* __restrict__ hb = (const fx4*)(h + (size_t)row0 * D_MODEL);

        float acc[4][N_MOD];
        #pragma unroll
        for (int i = 0; i < 4; ++i)
            #pragma unroll
            for (int m = 0; m < N_MOD; ++m) acc[i][m] = 0.f;

        #pragma unroll
        for (int c = 0; c < 4; ++c) {
            fx4 v0 = hb[0 * 256 + c * 64 + lane];
            fx4 v1 = hb[1 * 256 + c * 64 + lane];
            fx4 v2 = hb[2 * 256 + c * 64 + lane];
            fx4 v3 = hb[3 * 256 + c * 64 + lane];
            #pragma unroll
            for (int m = 0; m < N_MOD; ++m) {
                const fx4 w = wlds[m][c][lane];
                acc[0][m] += v0.x*w.x + v0.y*w.y + v0.z*w.z + v0.w*w.w;
                acc[1][m] += v1.x*w.x + v1.y*w.y + v1.z*w.z + v1.w*w.w;
                acc[2][m] += v2.x*w.x + v2.y*w.y + v2.z*w.z + v2.w*w.w;
                acc[3][m] += v3.x*w.x + v3.y*w.y + v3.z*w.z + v3.w*w.w;
            }
        }

        unsigned mask = 0;
        #pragma unroll
        for (int i = 0; i < 4; ++i) {
            // Fold 4 module streams into lane%4, then butterfly: 7 shuffles.
            const bool b0 = lane & 1;
            const float aa = (b0 ? acc[i][1] : acc[i][0])
                           + __shfl_xor(b0 ? acc[i][0] : acc[i][1], 1, 64);
            const float cc = (b0 ? acc[i][3] : acc[i][2])
                           + __shfl_xor(b0 ? acc[i][2] : acc[i][3], 1, 64);
            const bool b1 = lane & 2;
            float r = (b1 ? cc : aa) + __shfl_xor(b1 ? aa : cc, 2, 64);
            r += __shfl_xor(r, 4, 64);
            r += __shfl_xor(r, 8, 64);
            r += __shfl_xor(r, 16, 64);
            r += __shfl_xor(r, 32, 64);
            // r = logit of module lane&3, replicated per 4-lane group
            float mx = fmaxf(r, __shfl_xor(r, 1, 64));
            mx = fmaxf(mx, __shfl_xor(mx, 2, 64));
            const float ex = expf(r - mx);        // argmax lane: exactly 1.0
            float S = ex + __shfl_xor(ex, 1, 64);
            S += __shfl_xor(S, 2, 64);
            // prob_m > 0.5  <=>  m == argmax && S < 2  (ties -> S>=2 -> false)
            const bool hi = (r == mx) && (S < 2.0f);
            mask |= (hi ? 1u : 0u) << i;
        }

        // lanes 0-15 write 4 x 64B: module m = l>>2, row offset l&3
        const int m  = lane >> 2;
        const int rs = lane & 3;
        const unsigned mm = __shfl(mask, m, 64);  // lane m holds module m's mask
        if (lane < 16) {
            const bool hi = (mm >> rs) & 1;
            const float4 val = hi ? make_float4(0.5f, 0.5f, 0.f, 0.f)
                                  : make_float4(1.f, 0.f, 0.f, 0.f);
            out4[(size_t)m * B + row0 + rs] = val;
        }
    }
}

extern "C" void kernel_launch(void* const* d_in, const int* in_sizes, int n_in,
                              void* d_out, int out_size, void* d_ws, size_t ws_size,
                              hipStream_t stream) {
    const float* h  = (const float*)d_in[0];   // [B, 1024]
    const fx4*   Wg = (const fx4*)d_in[1];     // [1024, 1024] floats
    const float* Wr = (const float*)d_in[2];   // [4, 1024]
    float* out = (float*)d_out;                // [4][B][4]

    const int B = in_sizes[0] / D_MODEL;       // 32768

    float* Weff    = (float*)d_ws;                            // 16 KB
    fx4*   partial = (fx4*)((float*)d_ws + N_MOD * D_MODEL);  // 512 KB

    dim3 g1(EB, 4);
    weff_partial_kernel<<<g1, 256, 0, stream>>>(Wg, Wr, partial);
    weff_reduce_kernel<<<(N_MOD * D_MODEL) / 256, 256, 0, stream>>>(
        (const float*)partial, Weff);

    const int grid = (B + 4 * 4 - 1) / (4 * 4); // 2048 for B=32768
    router_main_kernel<<<grid, 256, 0, stream>>>(h, Weff, out, B);
}

// Round 12
// 114.498 us; speedup vs baseline: 2.0603x; 2.0603x over previous
//
#include <hip/hip_runtime.h>

#define D_MODEL 1024
#define N_MOD   4
#define EB      32     // e-chunks in stage 1
#define ECHUNK  32     // e per chunk
#define EPW     8      // e per esub-wave

typedef float fx4 __attribute__((ext_vector_type(4)));

// ============ Stage 1 (R8 verbatim): partial[m][eb][d] ============
__global__ __launch_bounds__(256) void weff_partial_kernel(
    const fx4* __restrict__ Wg4,   // [1024][256] fx4
    const float* __restrict__ Wr,  // [4][1024]
    fx4* __restrict__ partial4)    // [4][EB][256] fx4
{
    const int t    = threadIdx.x;
    const int esub = t >> 6;
    const int d4   = t & 63;
    const int eb   = blockIdx.x;
    const int dc   = blockIdx.y;
    const int d4g  = dc * 64 + d4;
    const int e0   = eb * ECHUNK + esub * EPW;

    fx4 acc[N_MOD];
    #pragma unroll
    for (int m = 0; m < N_MOD; ++m) acc[m] = (fx4)(0.f);
    #pragma unroll
    for (int k = 0; k < EPW; ++k) {
        const int e = e0 + k;
        const fx4 wg = Wg4[e * 256 + d4g];
        #pragma unroll
        for (int m = 0; m < N_MOD; ++m)
            acc[m] += Wr[m * D_MODEL + e] * wg;   // wave-uniform scalar Wr load
    }
    __shared__ fx4 red[4][N_MOD][64];
    #pragma unroll
    for (int m = 0; m < N_MOD; ++m) red[esub][m][d4] = acc[m];
    __syncthreads();
    const int m2 = t >> 6;
    partial4[(m2 * EB + eb) * 256 + d4g] =
        red[0][m2][d4] + red[1][m2][d4] + red[2][m2][d4] + red[3][m2][d4];
}

// ============ Main (R8 body; w4-init now reduces partial directly) ============
// w4[m][c] = sum_{eb=0..31} partial[m][eb][c*64+lane]  -- same ascending-eb
// order as the old stage2, so Weff values are bit-identical.
__global__ __launch_bounds__(256) void router_main_kernel(
    const float* __restrict__ h,        // [B, 1024]
    const fx4*   __restrict__ partial4, // [4][EB][256] fx4 (L2-resident, 512KB)
    float* __restrict__ out,            // [4][B][4]
    int B)
{
    const int lane = threadIdx.x & 63;
    const int wave = threadIdx.x >> 6;

    fx4 w4[N_MOD][4];
    #pragma unroll
    for (int m = 0; m < N_MOD; ++m) {
        #pragma unroll
        for (int c = 0; c < 4; ++c) {
            fx4 s = (fx4)(0.f);
            #pragma unroll 8
            for (int eb = 0; eb < EB; ++eb)
                s += partial4[(m * EB + eb) * 256 + c * 64 + lane]; // 1KB coalesced
            w4[m][c] = s;
        }
    }

    float4* __restrict__ out4 = (float4*)out;   // [4][B] float4s
    const int wid  = blockIdx.x * 4 + wave;
    const int step = gridDim.x * 4 * 8;

    for (int row0 = wid * 8; row0 < B; row0 += step) {
        unsigned mask = 0;
        #pragma unroll
        for (int i = 0; i < 8; ++i) {
            const int row = row0 + i;
            const fx4* __restrict__ h4 = (const fx4*)(h + (size_t)row * D_MODEL);
            fx4 v[4];
            #pragma unroll
            for (int c = 0; c < 4; ++c) v[c] = h4[c * 64 + lane];

            float acc[N_MOD] = {0.f, 0.f, 0.f, 0.f};
            #pragma unroll
            for (int c = 0; c < 4; ++c) {
                #pragma unroll
                for (int m = 0; m < N_MOD; ++m) {
                    acc[m] = fmaf(v[c].x, w4[m][c].x, acc[m]);
                    acc[m] = fmaf(v[c].y, w4[m][c].y, acc[m]);
                    acc[m] = fmaf(v[c].z, w4[m][c].z, acc[m]);
                    acc[m] = fmaf(v[c].w, w4[m][c].w, acc[m]);
                }
            }
            // Fold 4 streams into lane%4, then butterfly: 7 shuffles total.
            const bool b0 = lane & 1;
            float a  = (b0 ? acc[1] : acc[0]) + __shfl_xor(b0 ? acc[0] : acc[1], 1, 64);
            float cc = (b0 ? acc[3] : acc[2]) + __shfl_xor(b0 ? acc[2] : acc[3], 1, 64);
            const bool b1 = lane & 2;
            float r  = (b1 ? cc : a) + __shfl_xor(b1 ? a : cc, 2, 64);
            r += __shfl_xor(r, 4, 64);
            r += __shfl_xor(r, 8, 64);
            r += __shfl_xor(r, 16, 64);
            r += __shfl_xor(r, 32, 64);
            // r = logit of module lane&3 (replicated across each 4-lane group)
            float mx = fmaxf(r, __shfl_xor(r, 1, 64));
            mx = fmaxf(mx, __shfl_xor(mx, 2, 64));
            const float ex = expf(r - mx);       // argmax lane: exactly 1.0
            float S = ex + __shfl_xor(ex, 1, 64);
            S = S + __shfl_xor(S, 2, 64);
            // prob_m > 0.5  <=>  m == argmax  &&  S < 2
            const bool hi = (r == mx) && (S < 2.0f);
            mask |= (hi ? 1u : 0u) << i;
        }
        // lanes 0-31 write 4 full 128B lines: module m = l>>3, row offset l&7
        const int m = lane >> 3;
        const int rs = lane & 7;
        const unsigned mm = __shfl(mask, m, 64); // lane m holds module m's mask
        if (lane < 32) {
            const bool hi = (mm >> rs) & 1;
            const float4 val = hi ? make_float4(0.5f, 0.5f, 0.f, 0.f)
                                  : make_float4(1.f, 0.f, 0.f, 0.f);
            out4[(size_t)m * B + row0 + rs] = val;
        }
    }
}

extern "C" void kernel_launch(void* const* d_in, const int* in_sizes, int n_in,
                              void* d_out, int out_size, void* d_ws, size_t ws_size,
                              hipStream_t stream) {
    const float* h  = (const float*)d_in[0];   // [B, 1024]
    const fx4*   Wg = (const fx4*)d_in[1];     // [1024, 1024] floats
    const float* Wr = (const float*)d_in[2];   // [4, 1024]
    float* out = (float*)d_out;                // [4][B][4]

    const int B = in_sizes[0] / D_MODEL;       // 32768

    fx4* partial = (fx4*)((float*)d_ws + N_MOD * D_MODEL);  // 512 KB @ +16KB

    dim3 g1(EB, 4);
    weff_partial_kernel<<<g1, 256, 0, stream>>>(Wg, Wr, partial);

    const int grid = (B + 8 * 4 - 1) / (8 * 4); // 1024 for B=32768
    router_main_kernel<<<grid, 256, 0, stream>>>(h, partial, out, B);
}

// Round 13
// 31.827 us; speedup vs baseline: 7.4120x; 3.5975x over previous
//
#include <hip/hip_runtime.h>

#define D_MODEL 1024
#define N_MOD   4

typedef float fx4 __attribute__((ext_vector_type(4)));

// ============ Stage (single kernel, comm-free): Weff = Wr . Wg ============
// Grid: 128 blocks x 256 threads. Block b owns fx4-columns {2b, 2b+1}.
// Thread t: es = t>>1 (0..127 e-subgroup), c = t&1 (column within block).
// Loops k=0..7 over e = es + k*128 -> all 1024 e-rows covered.
// Wg is read exactly once grid-wide (32B/block/row; paired blocks share the
// 64B line via L2). In-block reduce: LDS fold 128->32, then half-wave shuffle.
__global__ __launch_bounds__(256) void weff_skinny_kernel(
    const fx4*   __restrict__ Wg4,   // [1024][256] fx4
    const float* __restrict__ Wr,    // [4][1024]
    fx4*         __restrict__ Weff4) // [4][256] fx4
{
    const int t   = threadIdx.x;
    const int es  = t >> 1;               // 0..127
    const int c   = t & 1;                // 0..1
    const int col = blockIdx.x * 2 + c;   // fx4-column 0..255

    fx4 acc[N_MOD];
    #pragma unroll
    for (int m = 0; m < N_MOD; ++m) acc[m] = (fx4)(0.f);

    #pragma unroll
    for (int k = 0; k < 8; ++k) {
        const int e = es + k * 128;
        const fx4 wg = Wg4[e * 256 + col];      // lane pairs: 32B contiguous
        #pragma unroll
        for (int m = 0; m < N_MOD; ++m)
            acc[m] += Wr[m * D_MODEL + e] * wg; // 128B coalesced, L1-hot
    }

    // LDS fold: 128 es -> 32 per (c,m) pair.
    __shared__ fx4 red[2][N_MOD][128];          // 16KB
    #pragma unroll
    for (int m = 0; m < N_MOD; ++m) red[c][m][es] = acc[m];
    __syncthreads();

    // 8 (c,m) pairs x 32 lanes: p = t>>5 (c2 = p&1, m2 = p>>1), e5 = t&31.
    const int p  = t >> 5;
    const int c2 = p & 1;
    const int m2 = p >> 1;
    const int e5 = t & 31;
    fx4 s = red[c2][m2][e5]      + red[c2][m2][e5 + 32]
          + red[c2][m2][e5 + 64] + red[c2][m2][e5 + 96];

    // Half-wave shuffle reduce (offsets <=16 stay within each 32-lane half).
    #pragma unroll
    for (int off = 16; off; off >>= 1) {
        s.x += __shfl_xor(s.x, off, 64);
        s.y += __shfl_xor(s.y, off, 64);
        s.z += __shfl_xor(s.z, off, 64);
        s.w += __shfl_xor(s.w, off, 64);
    }
    if (e5 == 0)
        Weff4[m2 * 256 + blockIdx.x * 2 + c2] = s;
}

// ============ Main (R8-proven, verbatim): 8 rows/wave ============
__global__ __launch_bounds__(256) void router_main_kernel(
    const float* __restrict__ h,     // [B, 1024]
    const float* __restrict__ Weff,  // [4, 1024]
    float* __restrict__ out,         // [4][B][4]
    int B)
{
    const int lane = threadIdx.x & 63;
    const int wave = threadIdx.x >> 6;

    fx4 w4[N_MOD][4];
    const fx4* __restrict__ W4 = (const fx4*)Weff;
    #pragma unroll
    for (int m = 0; m < N_MOD; ++m)
        #pragma unroll
        for (int c = 0; c < 4; ++c)
            w4[m][c] = W4[m * 256 + c * 64 + lane];

    float4* __restrict__ out4 = (float4*)out;   // [4][B] float4s
    const int wid  = blockIdx.x * 4 + wave;
    const int step = gridDim.x * 4 * 8;

    for (int row0 = wid * 8; row0 < B; row0 += step) {
        unsigned mask = 0;
        #pragma unroll
        for (int i = 0; i < 8; ++i) {
            const int row = row0 + i;
            const fx4* __restrict__ h4 = (const fx4*)(h + (size_t)row * D_MODEL);
            fx4 v[4];
            #pragma unroll
            for (int c = 0; c < 4; ++c) v[c] = h4[c * 64 + lane];

            float acc[N_MOD] = {0.f, 0.f, 0.f, 0.f};
            #pragma unroll
            for (int c = 0; c < 4; ++c) {
                #pragma unroll
                for (int m = 0; m < N_MOD; ++m) {
                    acc[m] = fmaf(v[c].x, w4[m][c].x, acc[m]);
                    acc[m] = fmaf(v[c].y, w4[m][c].y, acc[m]);
                    acc[m] = fmaf(v[c].z, w4[m][c].z, acc[m]);
                    acc[m] = fmaf(v[c].w, w4[m][c].w, acc[m]);
                }
            }
            // Fold 4 streams into lane%4, then butterfly: 7 shuffles total.
            const bool b0 = lane & 1;
            float a  = (b0 ? acc[1] : acc[0]) + __shfl_xor(b0 ? acc[0] : acc[1], 1, 64);
            float cc = (b0 ? acc[3] : acc[2]) + __shfl_xor(b0 ? acc[2] : acc[3], 1, 64);
            const bool b1 = lane & 2;
            float r  = (b1 ? cc : a) + __shfl_xor(b1 ? a : cc, 2, 64);
            r += __shfl_xor(r, 4, 64);
            r += __shfl_xor(r, 8, 64);
            r += __shfl_xor(r, 16, 64);
            r += __shfl_xor(r, 32, 64);
            // r = logit of module lane&3 (replicated across each 4-lane group)
            float mx = fmaxf(r, __shfl_xor(r, 1, 64));
            mx = fmaxf(mx, __shfl_xor(mx, 2, 64));
            const float ex = expf(r - mx);       // argmax lane: exactly 1.0
            float S = ex + __shfl_xor(ex, 1, 64);
            S = S + __shfl_xor(S, 2, 64);
            // prob_m > 0.5  <=>  m == argmax  &&  S < 2
            const bool hi = (r == mx) && (S < 2.0f);
            mask |= (hi ? 1u : 0u) << i;
        }
        // lanes 0-31 write 4 full 128B lines: module m = l>>3, row offset l&7
        const int m = lane >> 3;
        const int rs = lane & 7;
        const unsigned mm = __shfl(mask, m, 64); // lane m holds module m's mask
        if (lane < 32) {
            const bool hi = (mm >> rs) & 1;
            const float4 val = hi ? make_float4(0.5f, 0.5f, 0.f, 0.f)
                                  : make_float4(1.f, 0.f, 0.f, 0.f);
            out4[(size_t)m * B + row0 + rs] = val;
        }
    }
}

extern "C" void kernel_launch(void* const* d_in, const int* in_sizes, int n_in,
                              void* d_out, int out_size, void* d_ws, size_t ws_size,
                              hipStream_t stream) {
    const float* h  = (const float*)d_in[0];   // [B, 1024]
    const fx4*   Wg = (const fx4*)d_in[1];     // [1024, 1024] floats
    const float* Wr = (const float*)d_in[2];   // [4, 1024]
    float* out = (float*)d_out;                // [4][B][4]

    const int B = in_sizes[0] / D_MODEL;       // 32768

    float* Weff = (float*)d_ws;                // 16 KB

    weff_skinny_kernel<<<128, 256, 0, stream>>>(Wg, Wr, (fx4*)Weff);

    const int grid = (B + 8 * 4 - 1) / (8 * 4); // 1024 for B=32768
    router_main_kernel<<<grid, 256, 0, stream>>>(h, Weff, out, B);
}